// Round 21
// baseline (461.419 us; speedup 1.0000x reference)
//
#include <hip/hip_runtime.h>

#define B_ 128
#define T_ 512
#define D_ 512
#define H_ 64
#define N3 192   // 3*H

#if __has_builtin(__builtin_amdgcn_rcpf)
#define RCP(x) __builtin_amdgcn_rcpf(x)
#else
#define RCP(x) (1.0f / (x))
#endif

typedef _Float16 h2v __attribute__((ext_vector_type(2)));
typedef _Float16 f16x8 __attribute__((ext_vector_type(8)));
typedef float f32x4 __attribute__((ext_vector_type(4)));

__device__ __forceinline__ float sigm_f(float x) {
  return RCP(1.0f + __expf(-x));
}
__device__ __forceinline__ float tanh_f(float x) {
  float e = __expf(-2.0f * fabsf(x));
  float t = (1.0f - e) * RCP(1.0f + e);
  return copysignf(t, x);
}

// DPP lane-group sums (bound_ctrl=1).
template <int CTRL>
__device__ __forceinline__ float dpp_add(float v) {
  int t = __builtin_amdgcn_update_dpp(0, __float_as_int(v), CTRL, 0xF, 0xF, true);
  return v + __int_as_float(t);
}
__device__ __forceinline__ float red4(float v) {
  v = dpp_add<0xB1>(v);
  v = dpp_add<0x4E>(v);
  return v;
}
// 8-lane sum (r12-verified): xor1, xor2, then row_half_mirror acts as xor4
// once quad-uniform.
__device__ __forceinline__ float red8(float v) {
  v = dpp_add<0xB1>(v);
  v = dpp_add<0x4E>(v);
  v = dpp_add<0x141>(v);
  return v;
}

__device__ __forceinline__ void dot4acc(int4 w, int4 h, float& s0, float& s1) {
  s0 = __builtin_amdgcn_fdot2(__builtin_bit_cast(h2v, w.x),
                              __builtin_bit_cast(h2v, h.x), s0, false);
  s1 = __builtin_amdgcn_fdot2(__builtin_bit_cast(h2v, w.y),
                              __builtin_bit_cast(h2v, h.y), s1, false);
  s0 = __builtin_amdgcn_fdot2(__builtin_bit_cast(h2v, w.z),
                              __builtin_bit_cast(h2v, h.z), s0, false);
  s1 = __builtin_amdgcn_fdot2(__builtin_bit_cast(h2v, w.w),
                              __builtin_bit_cast(h2v, h.w), s1, false);
}
__device__ __forceinline__ void dot8reg(const int* w, int4 a, int4 b,
                                        float& s0, float& s1) {
  s0 = __builtin_amdgcn_fdot2(__builtin_bit_cast(h2v, w[0]),
                              __builtin_bit_cast(h2v, a.x), s0, false);
  s1 = __builtin_amdgcn_fdot2(__builtin_bit_cast(h2v, w[1]),
                              __builtin_bit_cast(h2v, a.y), s1, false);
  s0 = __builtin_amdgcn_fdot2(__builtin_bit_cast(h2v, w[2]),
                              __builtin_bit_cast(h2v, a.z), s0, false);
  s1 = __builtin_amdgcn_fdot2(__builtin_bit_cast(h2v, w[3]),
                              __builtin_bit_cast(h2v, a.w), s1, false);
  s0 = __builtin_amdgcn_fdot2(__builtin_bit_cast(h2v, w[4]),
                              __builtin_bit_cast(h2v, b.x), s0, false);
  s1 = __builtin_amdgcn_fdot2(__builtin_bit_cast(h2v, w[5]),
                              __builtin_bit_cast(h2v, b.y), s1, false);
  s0 = __builtin_amdgcn_fdot2(__builtin_bit_cast(h2v, w[6]),
                              __builtin_bit_cast(h2v, b.z), s0, false);
  s1 = __builtin_amdgcn_fdot2(__builtin_bit_cast(h2v, w[7]),
                              __builtin_bit_cast(h2v, b.w), s1, false);
}

#define KEEP(x) asm volatile("" : "+v"(x))

// lgkmcnt(0)+s_barrier only (no vmcnt drain).
#define TICK_BARRIER() asm volatile("s_waitcnt lgkmcnt(0)\ns_barrier" ::: "memory")

// ---------------- pass 1 (r18, verified): gi0 = X @ W0ih^T + bias, MFMA ----------------
__global__ __launch_bounds__(256) void gemm_kernel(
    const float* __restrict__ x,     // [B,T,D]
    const float* __restrict__ w0ih,  // [N3,D]
    const float* __restrict__ b0ih,  // [N3]
    const float* __restrict__ b0hh,  // [N3]
    float* __restrict__ gi0,         // [B,Tc,N3]
    int* __restrict__ act,           // [T]
    int t0, int Tc) {
  __shared__ _Float16 Xs[64][72];
  __shared__ _Float16 Ws[64][72];
  __shared__ unsigned char sflag[64];

  const int tid = threadIdx.x;
  const int bid = blockIdx.x;
  const int nt = bid % 3;
  const int mt = bid / 3;
  const int tpc = Tc >> 6;
  const int b  = mt / tpc;
  const int tt = mt % tpc;
  const int c0 = nt * 64;

  const int lane = tid & 63;
  const int wid  = tid >> 6;
  const int wm = (wid >> 1) * 32;
  const int wn = (wid & 1) * 32;
  const int l15 = lane & 15;
  const int l4  = lane >> 4;

  const float* xbase = x + ((size_t)b * T_ + t0 + tt * 64) * D_;
  const float* wbase = w0ih + (size_t)c0 * D_;

  const int srow = tid >> 2;
  const int scg  = (tid & 3) << 4;
  const float* xrow = xbase + (size_t)srow * D_;
  const float* wrow = wbase + (size_t)srow * D_;

  f32x4 acc[2][2];
#pragma unroll
  for (int mi = 0; mi < 2; ++mi)
#pragma unroll
    for (int ni = 0; ni < 2; ++ni) {
      acc[mi][ni].x = 0.f; acc[mi][ni].y = 0.f;
      acc[mi][ni].z = 0.f; acc[mi][ni].w = 0.f;
    }

  bool f = false;

  for (int kt = 0; kt < D_ / 64; ++kt) {
    const int k0 = kt * 64 + scg;
    float4 xa = *(const float4*)&xrow[k0];
    float4 xb = *(const float4*)&xrow[k0 + 4];
    float4 xc = *(const float4*)&xrow[k0 + 8];
    float4 xd = *(const float4*)&xrow[k0 + 12];
    float4 wa = *(const float4*)&wrow[k0];
    float4 wb = *(const float4*)&wrow[k0 + 4];
    float4 wc = *(const float4*)&wrow[k0 + 8];
    float4 wd = *(const float4*)&wrow[k0 + 12];
    f |= (xa.x != 0.f) | (xa.y != 0.f) | (xa.z != 0.f) | (xa.w != 0.f) |
         (xb.x != 0.f) | (xb.y != 0.f) | (xb.z != 0.f) | (xb.w != 0.f) |
         (xc.x != 0.f) | (xc.y != 0.f) | (xc.z != 0.f) | (xc.w != 0.f) |
         (xd.x != 0.f) | (xd.y != 0.f) | (xd.z != 0.f) | (xd.w != 0.f);
    __syncthreads();
    {
      f16x8 p0 = {(_Float16)xa.x, (_Float16)xa.y, (_Float16)xa.z, (_Float16)xa.w,
                  (_Float16)xb.x, (_Float16)xb.y, (_Float16)xb.z, (_Float16)xb.w};
      f16x8 p1 = {(_Float16)xc.x, (_Float16)xc.y, (_Float16)xc.z, (_Float16)xc.w,
                  (_Float16)xd.x, (_Float16)xd.y, (_Float16)xd.z, (_Float16)xd.w};
      *(f16x8*)&Xs[srow][scg] = p0;
      *(f16x8*)&Xs[srow][scg + 8] = p1;
      f16x8 q0 = {(_Float16)wa.x, (_Float16)wa.y, (_Float16)wa.z, (_Float16)wa.w,
                  (_Float16)wb.x, (_Float16)wb.y, (_Float16)wb.z, (_Float16)wb.w};
      f16x8 q1 = {(_Float16)wc.x, (_Float16)wc.y, (_Float16)wc.z, (_Float16)wc.w,
                  (_Float16)wd.x, (_Float16)wd.y, (_Float16)wd.z, (_Float16)wd.w};
      *(f16x8*)&Ws[srow][scg] = q0;
      *(f16x8*)&Ws[srow][scg + 8] = q1;
    }
    __syncthreads();
#pragma unroll
    for (int ks = 0; ks < 2; ++ks) {
      const int kb = ks * 32 + l4 * 8;
      f16x8 a0 = *(const f16x8*)&Xs[wm + l15][kb];
      f16x8 a1 = *(const f16x8*)&Xs[wm + 16 + l15][kb];
      f16x8 b0 = *(const f16x8*)&Ws[wn + l15][kb];
      f16x8 b1 = *(const f16x8*)&Ws[wn + 16 + l15][kb];
      acc[0][0] = __builtin_amdgcn_mfma_f32_16x16x32_f16(a0, b0, acc[0][0], 0, 0, 0);
      acc[0][1] = __builtin_amdgcn_mfma_f32_16x16x32_f16(a0, b1, acc[0][1], 0, 0, 0);
      acc[1][0] = __builtin_amdgcn_mfma_f32_16x16x32_f16(a1, b0, acc[1][0], 0, 0, 0);
      acc[1][1] = __builtin_amdgcn_mfma_f32_16x16x32_f16(a1, b1, acc[1][1], 0, 0, 0);
    }
  }

  const int cA = c0 + wn + l15;
  const int cB = c0 + wn + 16 + l15;
  const float bias0 = b0ih[cA] + ((cA < 128) ? b0hh[cA] : 0.f);
  const float bias1 = b0ih[cB] + ((cB < 128) ? b0hh[cB] : 0.f);
  const size_t rowbase = (size_t)b * Tc + tt * 64;
#pragma unroll
  for (int mi = 0; mi < 2; ++mi)
#pragma unroll
    for (int r = 0; r < 4; ++r) {
      const int m = wm + mi * 16 + l4 * 4 + r;
      float* orow = &gi0[(rowbase + m) * N3 + c0 + wn];
      orow[l15]      = acc[mi][0][r] + bias0;
      orow[16 + l15] = acc[mi][1][r] + bias1;
    }

  if (tid < 64) sflag[tid] = 0;
  __syncthreads();
  if (f) sflag[srow] = 1;
  __syncthreads();
  if (tid < 64 && sflag[tid]) act[t0 + tt * 64 + tid] = 1;
}

// ------------- pass 2: r20 layer-pipelined registerized scan @ 16 waves -------------
// r20 diagnosis: tick 1742 cyc vs ~550 issue -> chain-latency exposed at 2.5
// waves/SIMD. This round: 1024 threads = 16 waves = 4/SIMD for TLP. Groups:
// grp0 = 4 waves (16-wide, red4), grp1 = 4 waves (16-wide, red4, unchanged),
// grp2 = 8 waves (8-wide, red8 -- r12-verified ladder). All weights stay in
// registers (max 48 dwords/thread, under the 128-reg cap at 4 waves/SIMD).
// Schedule/sync/math identical to r20.
__global__ __launch_bounds__(1024) void scan_kernel(
    const float* __restrict__ gi0,   // [B,Tc,N3]
    const float* __restrict__ w0hh, const float* __restrict__ w1ih,
    const float* __restrict__ w1hh, const float* __restrict__ w2ih,
    const float* __restrict__ w2hh,
    const float* __restrict__ b0hh, const float* __restrict__ b1ih,
    const float* __restrict__ b1hh, const float* __restrict__ b2ih,
    const float* __restrict__ b2hh,
    const int* __restrict__ act,     // [T]
    float* __restrict__ hstate,      // [3,B,H]
    float* __restrict__ out,         // [B,T,H]
    int t0, int Tc) {
  const int b   = blockIdx.x;
  const int tid = threadIdx.x;

  __shared__ __align__(16) _Float16 s_h[3][2][H_];    // [layer][parity][unit]
  __shared__ int s_act[T_];

  for (int i = tid; i < Tc; i += 1024) s_act[i] = act[t0 + i];

  // groups: waves 0-3 = grp0, 4-7 = grp1, 8-15 = grp2
  const int grp = (tid < 256) ? 0 : (tid < 512) ? 1 : 2;
  const int lt  = tid - ((grp == 0) ? 0 : (grp == 1) ? 256 : 512);
  const int jj  = (grp == 2) ? (lt >> 3) : (lt >> 2);
  const int gg  = (grp == 2) ? (lt & 7) : (lt & 3);

  if (tid < H_) {
    float v0 = (t0 == 0) ? 0.f : hstate[0 * B_ * H_ + b * H_ + tid];
    float v1 = (t0 == 0) ? 0.f : hstate[1 * B_ * H_ + b * H_ + tid];
    float v2 = (t0 == 0) ? 0.f : hstate[2 * B_ * H_ + b * H_ + tid];
    s_h[0][0][tid] = (_Float16)v0; s_h[0][1][tid] = (_Float16)v0;
    s_h[1][0][tid] = (_Float16)v1; s_h[1][1][tid] = (_Float16)v1;
    s_h[2][0][tid] = (_Float16)v2; s_h[2][1][tid] = (_Float16)v2;
  }
  float hreg = (t0 == 0) ? 0.f : hstate[grp * B_ * H_ + b * H_ + jj];

  // ---- register weights (f16x2 dwords) ----
  int rih[3][8];   // grp0: W0hh 16-wide | grp1: W1ih 16-wide | (grp2 unused)
  int rhh[3][8];   // grp1: W1hh 16-wide
  int4 sih[3], shh[3];  // grp2: W2ih / W2hh 8-wide
  if (grp == 2) {
#pragma unroll
    for (int r = 0; r < 3; ++r) {
      const float* si = w2ih + (size_t)(jj + 64 * r) * H_ + 8 * gg;
      const float* sh = w2hh + (size_t)(jj + 64 * r) * H_ + 8 * gg;
      int tmpi[4], tmph[4];
#pragma unroll
      for (int q = 0; q < 4; ++q) {
        float2 fi = *(const float2*)(si + 2 * q);
        float2 fh = *(const float2*)(sh + 2 * q);
        h2v pi = {(_Float16)fi.x, (_Float16)fi.y};
        h2v ph = {(_Float16)fh.x, (_Float16)fh.y};
        tmpi[q] = __builtin_bit_cast(int, pi);
        tmph[q] = __builtin_bit_cast(int, ph);
      }
      sih[r] = make_int4(tmpi[0], tmpi[1], tmpi[2], tmpi[3]);
      shh[r] = make_int4(tmph[0], tmph[1], tmph[2], tmph[3]);
    }
#pragma unroll
    for (int r = 0; r < 3; ++r) {
      KEEP(sih[r].x); KEEP(sih[r].y); KEEP(sih[r].z); KEEP(sih[r].w);
      KEEP(shh[r].x); KEEP(shh[r].y); KEEP(shh[r].z); KEEP(shh[r].w);
    }
  } else {
    const float* ihsrc = (grp == 0) ? w0hh : w1ih;
    const float* hhsrc = (grp == 0) ? w0hh : w1hh;  // grp0: rhh unused dummy
#pragma unroll
    for (int r = 0; r < 3; ++r) {
      const float* si = ihsrc + (size_t)(jj + 64 * r) * H_ + 16 * gg;
      const float* sh = hhsrc + (size_t)(jj + 64 * r) * H_ + 16 * gg;
#pragma unroll
      for (int q = 0; q < 8; ++q) {
        float2 fi = *(const float2*)(si + 2 * q);
        h2v pi = {(_Float16)fi.x, (_Float16)fi.y};
        rih[r][q] = __builtin_bit_cast(int, pi);
        if (grp == 1) {
          float2 fh = *(const float2*)(sh + 2 * q);
          h2v ph = {(_Float16)fh.x, (_Float16)fh.y};
          rhh[r][q] = __builtin_bit_cast(int, ph);
        }
      }
    }
#pragma unroll
    for (int r = 0; r < 3; ++r)
#pragma unroll
      for (int q = 0; q < 8; ++q) {
        KEEP(rih[r][q]);
        if (grp == 1) KEEP(rhh[r][q]);
      }
  }

  // biases: [0]=R combined, [1]=Z combined, [2]=ih_N, [3]=hh_N
  float bsv[4];
  if (grp == 0) {
    bsv[0] = 0.f; bsv[1] = 0.f; bsv[2] = 0.f;
    bsv[3] = b0hh[jj + 128];
  } else if (grp == 1) {
    bsv[0] = b1ih[jj] + b1hh[jj];
    bsv[1] = b1ih[jj + 64] + b1hh[jj + 64];
    bsv[2] = b1ih[jj + 128]; bsv[3] = b1hh[jj + 128];
  } else {
    bsv[0] = b2ih[jj] + b2hh[jj];
    bsv[1] = b2ih[jj + 64] + b2hh[jj + 64];
    bsv[2] = b2ih[jj + 128]; bsv[3] = b2hh[jj + 128];
  }

  const float* gib = gi0 + (size_t)b * Tc * N3;
  float giR = 0.f, giZ = 0.f, giN = 0.f;
  if (grp == 0) { giR = gib[jj]; giZ = gib[jj + 64]; giN = gib[jj + 128]; }

  __syncthreads();   // initial full barrier

  for (int i = 0; i < Tc + 2; ++i) {
    const int p = i & 1;
    if (grp == 0) {
      if (i < Tc) {
        const int4* hp = (const int4*)s_h[0][p ^ 1];
        int4 x0 = hp[2 * gg], x1 = hp[2 * gg + 1];
        float R0 = 0, R1 = 0, Z0 = 0, Z1 = 0, N0 = 0, N1 = 0;
        dot8reg(rih[0], x0, x1, R0, R1);
        dot8reg(rih[1], x0, x1, Z0, Z1);
        dot8reg(rih[2], x0, x1, N0, N1);
        float dR = red4(R0 + R1);
        float dZ = red4(Z0 + Z1);
        float dN = red4(N0 + N1) + bsv[3];
        bool a = (s_act[i] != 0);
        float r = sigm_f(giR + dR);
        float z = sigm_f(giZ + dZ);
        float n = tanh_f(giN + r * dN);
        float hn = (1.0f - z) * n + z * hreg;
        hreg = a ? hn : hreg;
        if (gg == 0) s_h[0][p][jj] = (_Float16)hreg;
        int tn = (i + 1 < Tc) ? i + 1 : i;   // prefetch across barrier
        giR = gib[(size_t)tn * N3 + jj];
        giZ = gib[(size_t)tn * N3 + jj + 64];
        giN = gib[(size_t)tn * N3 + jj + 128];
      }
    } else if (grp == 1) {
      if (i >= 1 && i <= Tc) {
        const int4* h0p = (const int4*)s_h[0][p ^ 1];
        const int4* h1p = (const int4*)s_h[1][p ^ 1];
        int4 x0 = h0p[2 * gg], x1 = h0p[2 * gg + 1];
        int4 y0 = h1p[2 * gg], y1 = h1p[2 * gg + 1];
        float vR0 = 0, vR1 = 0, vZ0 = 0, vZ1 = 0;
        float iN0 = 0, iN1 = 0, hN0 = 0, hN1 = 0;
        dot8reg(rih[0], x0, x1, vR0, vR1);
        dot8reg(rhh[0], y0, y1, vR0, vR1);
        dot8reg(rih[1], x0, x1, vZ0, vZ1);
        dot8reg(rhh[1], y0, y1, vZ0, vZ1);
        dot8reg(rih[2], x0, x1, iN0, iN1);
        dot8reg(rhh[2], y0, y1, hN0, hN1);
        float sR = red4(vR0 + vR1) + bsv[0];
        float sZ = red4(vZ0 + vZ1) + bsv[1];
        float iN = red4(iN0 + iN1) + bsv[2];
        float hN = red4(hN0 + hN1) + bsv[3];
        bool a = (s_act[i - 1] != 0);
        float r = sigm_f(sR);
        float z = sigm_f(sZ);
        float n = tanh_f(iN + r * hN);
        float hn = (1.0f - z) * n + z * hreg;
        hreg = a ? hn : hreg;
        if (gg == 0) s_h[1][p][jj] = (_Float16)hreg;
      }
    } else {
      if (i >= 2) {
        const int4* h1p = (const int4*)s_h[1][p ^ 1];
        const int4* h2p = (const int4*)s_h[2][p ^ 1];
        int4 x0 = h1p[gg];
        int4 y0 = h2p[gg];
        float vR0 = 0, vR1 = 0, vZ0 = 0, vZ1 = 0;
        float iN0 = 0, iN1 = 0, hN0 = 0, hN1 = 0;
        dot4acc(sih[0], x0, vR0, vR1);
        dot4acc(shh[0], y0, vR0, vR1);
        dot4acc(sih[1], x0, vZ0, vZ1);
        dot4acc(shh[1], y0, vZ0, vZ1);
        dot4acc(sih[2], x0, iN0, iN1);
        dot4acc(shh[2], y0, hN0, hN1);
        float sR = red8(vR0 + vR1) + bsv[0];
        float sZ = red8(vZ0 + vZ1) + bsv[1];
        float iN = red8(iN0 + iN1) + bsv[2];
        float hN = red8(hN0 + hN1) + bsv[3];
        bool a = (s_act[i - 2] != 0);
        float r = sigm_f(sR);
        float z = sigm_f(sZ);
        float n = tanh_f(iN + r * hN);
        float hn = (1.0f - z) * n + z * hreg;
        hreg = a ? hn : hreg;
        if (gg == 0) {
          s_h[2][p][jj] = (_Float16)hreg;
          out[((size_t)b * T_ + t0 + (i - 2)) * H_ + jj] = a ? hreg : 0.0f;
        }
      }
    }
    TICK_BARRIER();   // lgkmcnt(0)+s_barrier only
  }

  if (gg == 0) hstate[grp * B_ * H_ + b * H_ + jj] = hreg;
}

extern "C" void kernel_launch(void* const* d_in, const int* in_sizes, int n_in,
                              void* d_out, int out_size, void* d_ws, size_t ws_size,
                              hipStream_t stream) {
  const float* x    = (const float*)d_in[0];
  const float* w0ih = (const float*)d_in[1];
  const float* w0hh = (const float*)d_in[2];
  const float* b0ih = (const float*)d_in[3];
  const float* b0hh = (const float*)d_in[4];
  const float* w1ih = (const float*)d_in[5];
  const float* w1hh = (const float*)d_in[6];
  const float* b1ih = (const float*)d_in[7];
  const float* b1hh = (const float*)d_in[8];
  const float* w2ih = (const float*)d_in[9];
  const float* w2hh = (const float*)d_in[10];
  const float* b2ih = (const float*)d_in[11];
  const float* b2hh = (const float*)d_in[12];
  float* out = (float*)d_out;

  char* p = (char*)d_ws;
  int* act      = (int*)p;    p += 4096;
  float* hstate = (float*)p;  p += (size_t)3 * B_ * H_ * 4;
  size_t fixed = (size_t)(p - (char*)d_ws);

  int Tc = T_;
  while (Tc > 64 && fixed + (size_t)B_ * Tc * N3 * 4 > ws_size) Tc >>= 1;
  float* gi0 = (float*)p;

  hipMemsetAsync(act, 0, T_ * sizeof(int), stream);
  for (int t0 = 0; t0 < T_; t0 += Tc) {
    gemm_kernel<<<dim3(B_ * (Tc / 64) * 3), 256, 0, stream>>>(
        x, w0ih, b0ih, b0hh, gi0, act, t0, Tc);
    scan_kernel<<<B_, 1024, 0, stream>>>(
        gi0, w0hh, w1ih, w1hh, w2ih, w2hh,
        b0hh, b1ih, b1hh, b2ih, b2hh, act, hstate, out, t0, Tc);
  }
}

// Round 22
// 433.212 us; speedup vs baseline: 1.0651x; 1.0651x over previous
//
#include <hip/hip_runtime.h>

#define B_ 128
#define T_ 512
#define D_ 512
#define H_ 64
#define N3 192   // 3*H

#if __has_builtin(__builtin_amdgcn_rcpf)
#define RCP(x) __builtin_amdgcn_rcpf(x)
#else
#define RCP(x) (1.0f / (x))
#endif

typedef _Float16 h2v __attribute__((ext_vector_type(2)));
typedef _Float16 f16x8 __attribute__((ext_vector_type(8)));
typedef float f32x4 __attribute__((ext_vector_type(4)));

__device__ __forceinline__ float sigm_f(float x) {
  return RCP(1.0f + __expf(-x));
}
__device__ __forceinline__ float tanh_f(float x) {
  float e = __expf(-2.0f * fabsf(x));
  float t = (1.0f - e) * RCP(1.0f + e);
  return copysignf(t, x);
}

// DPP lane-group sums (bound_ctrl=1).
template <int CTRL>
__device__ __forceinline__ float dpp_add(float v) {
  int t = __builtin_amdgcn_update_dpp(0, __float_as_int(v), CTRL, 0xF, 0xF, true);
  return v + __int_as_float(t);
}
__device__ __forceinline__ float red2(float v) { return dpp_add<0xB1>(v); }
__device__ __forceinline__ float red4(float v) {
  v = dpp_add<0xB1>(v);
  v = dpp_add<0x4E>(v);
  return v;
}

__device__ __forceinline__ void dot8reg(const int* w, int4 a, int4 b,
                                        float& s0, float& s1) {
  s0 = __builtin_amdgcn_fdot2(__builtin_bit_cast(h2v, w[0]),
                              __builtin_bit_cast(h2v, a.x), s0, false);
  s1 = __builtin_amdgcn_fdot2(__builtin_bit_cast(h2v, w[1]),
                              __builtin_bit_cast(h2v, a.y), s1, false);
  s0 = __builtin_amdgcn_fdot2(__builtin_bit_cast(h2v, w[2]),
                              __builtin_bit_cast(h2v, a.z), s0, false);
  s1 = __builtin_amdgcn_fdot2(__builtin_bit_cast(h2v, w[3]),
                              __builtin_bit_cast(h2v, a.w), s1, false);
  s0 = __builtin_amdgcn_fdot2(__builtin_bit_cast(h2v, w[4]),
                              __builtin_bit_cast(h2v, b.x), s0, false);
  s1 = __builtin_amdgcn_fdot2(__builtin_bit_cast(h2v, w[5]),
                              __builtin_bit_cast(h2v, b.y), s1, false);
  s0 = __builtin_amdgcn_fdot2(__builtin_bit_cast(h2v, w[6]),
                              __builtin_bit_cast(h2v, b.z), s0, false);
  s1 = __builtin_amdgcn_fdot2(__builtin_bit_cast(h2v, w[7]),
                              __builtin_bit_cast(h2v, b.w), s1, false);
}
__device__ __forceinline__ void dot16reg(const int* w, int4 a, int4 b,
                                         int4 c, int4 d, float& s0, float& s1) {
  dot8reg(w, a, b, s0, s1);
  dot8reg(w + 8, c, d, s0, s1);
}

#define KEEP(x) asm volatile("" : "+v"(x))

// lgkmcnt(0)+s_barrier only (no vmcnt drain).
#define TICK_BARRIER() asm volatile("s_waitcnt lgkmcnt(0)\ns_barrier" ::: "memory")

// ---------------- pass 1 (r18, verified): gi0 = X @ W0ih^T + bias, MFMA ----------------
__global__ __launch_bounds__(256) void gemm_kernel(
    const float* __restrict__ x,     // [B,T,D]
    const float* __restrict__ w0ih,  // [N3,D]
    const float* __restrict__ b0ih,  // [N3]
    const float* __restrict__ b0hh,  // [N3]
    float* __restrict__ gi0,         // [B,Tc,N3]
    int* __restrict__ act,           // [T]
    int t0, int Tc) {
  __shared__ _Float16 Xs[64][72];
  __shared__ _Float16 Ws[64][72];
  __shared__ unsigned char sflag[64];

  const int tid = threadIdx.x;
  const int bid = blockIdx.x;
  const int nt = bid % 3;
  const int mt = bid / 3;
  const int tpc = Tc >> 6;
  const int b  = mt / tpc;
  const int tt = mt % tpc;
  const int c0 = nt * 64;

  const int lane = tid & 63;
  const int wid  = tid >> 6;
  const int wm = (wid >> 1) * 32;
  const int wn = (wid & 1) * 32;
  const int l15 = lane & 15;
  const int l4  = lane >> 4;

  const float* xbase = x + ((size_t)b * T_ + t0 + tt * 64) * D_;
  const float* wbase = w0ih + (size_t)c0 * D_;

  const int srow = tid >> 2;
  const int scg  = (tid & 3) << 4;
  const float* xrow = xbase + (size_t)srow * D_;
  const float* wrow = wbase + (size_t)srow * D_;

  f32x4 acc[2][2];
#pragma unroll
  for (int mi = 0; mi < 2; ++mi)
#pragma unroll
    for (int ni = 0; ni < 2; ++ni) {
      acc[mi][ni].x = 0.f; acc[mi][ni].y = 0.f;
      acc[mi][ni].z = 0.f; acc[mi][ni].w = 0.f;
    }

  bool f = false;

  for (int kt = 0; kt < D_ / 64; ++kt) {
    const int k0 = kt * 64 + scg;
    float4 xa = *(const float4*)&xrow[k0];
    float4 xb = *(const float4*)&xrow[k0 + 4];
    float4 xc = *(const float4*)&xrow[k0 + 8];
    float4 xd = *(const float4*)&xrow[k0 + 12];
    float4 wa = *(const float4*)&wrow[k0];
    float4 wb = *(const float4*)&wrow[k0 + 4];
    float4 wc = *(const float4*)&wrow[k0 + 8];
    float4 wd = *(const float4*)&wrow[k0 + 12];
    f |= (xa.x != 0.f) | (xa.y != 0.f) | (xa.z != 0.f) | (xa.w != 0.f) |
         (xb.x != 0.f) | (xb.y != 0.f) | (xb.z != 0.f) | (xb.w != 0.f) |
         (xc.x != 0.f) | (xc.y != 0.f) | (xc.z != 0.f) | (xc.w != 0.f) |
         (xd.x != 0.f) | (xd.y != 0.f) | (xd.z != 0.f) | (xd.w != 0.f);
    __syncthreads();
    {
      f16x8 p0 = {(_Float16)xa.x, (_Float16)xa.y, (_Float16)xa.z, (_Float16)xa.w,
                  (_Float16)xb.x, (_Float16)xb.y, (_Float16)xb.z, (_Float16)xb.w};
      f16x8 p1 = {(_Float16)xc.x, (_Float16)xc.y, (_Float16)xc.z, (_Float16)xc.w,
                  (_Float16)xd.x, (_Float16)xd.y, (_Float16)xd.z, (_Float16)xd.w};
      *(f16x8*)&Xs[srow][scg] = p0;
      *(f16x8*)&Xs[srow][scg + 8] = p1;
      f16x8 q0 = {(_Float16)wa.x, (_Float16)wa.y, (_Float16)wa.z, (_Float16)wa.w,
                  (_Float16)wb.x, (_Float16)wb.y, (_Float16)wb.z, (_Float16)wb.w};
      f16x8 q1 = {(_Float16)wc.x, (_Float16)wc.y, (_Float16)wc.z, (_Float16)wc.w,
                  (_Float16)wd.x, (_Float16)wd.y, (_Float16)wd.z, (_Float16)wd.w};
      *(f16x8*)&Ws[srow][scg] = q0;
      *(f16x8*)&Ws[srow][scg + 8] = q1;
    }
    __syncthreads();
#pragma unroll
    for (int ks = 0; ks < 2; ++ks) {
      const int kb = ks * 32 + l4 * 8;
      f16x8 a0 = *(const f16x8*)&Xs[wm + l15][kb];
      f16x8 a1 = *(const f16x8*)&Xs[wm + 16 + l15][kb];
      f16x8 b0 = *(const f16x8*)&Ws[wn + l15][kb];
      f16x8 b1 = *(const f16x8*)&Ws[wn + 16 + l15][kb];
      acc[0][0] = __builtin_amdgcn_mfma_f32_16x16x32_f16(a0, b0, acc[0][0], 0, 0, 0);
      acc[0][1] = __builtin_amdgcn_mfma_f32_16x16x32_f16(a0, b1, acc[0][1], 0, 0, 0);
      acc[1][0] = __builtin_amdgcn_mfma_f32_16x16x32_f16(a1, b0, acc[1][0], 0, 0, 0);
      acc[1][1] = __builtin_amdgcn_mfma_f32_16x16x32_f16(a1, b1, acc[1][1], 0, 0, 0);
    }
  }

  const int cA = c0 + wn + l15;
  const int cB = c0 + wn + 16 + l15;
  const float bias0 = b0ih[cA] + ((cA < 128) ? b0hh[cA] : 0.f);
  const float bias1 = b0ih[cB] + ((cB < 128) ? b0hh[cB] : 0.f);
  const size_t rowbase = (size_t)b * Tc + tt * 64;
#pragma unroll
  for (int mi = 0; mi < 2; ++mi)
#pragma unroll
    for (int r = 0; r < 4; ++r) {
      const int m = wm + mi * 16 + l4 * 4 + r;
      float* orow = &gi0[(rowbase + m) * N3 + c0 + wn];
      orow[l15]      = acc[mi][0][r] + bias0;
      orow[16 + l15] = acc[mi][1][r] + bias1;
    }

  if (tid < 64) sflag[tid] = 0;
  __syncthreads();
  if (f) sflag[srow] = 1;
  __syncthreads();
  if (tid < 64 && sflag[tid]) act[t0 + tt * 64 + tid] = 1;
}

// ------------- pass 2: r20 scan (verified best, 373us) + gi-prefetch hoist -------------
// 640 thr = 10 waves: grp0 = 2 waves (32-wide segs, red2), grp1 = 4 waves
// (16-wide, red4), grp2 = 4 waves (16-wide, red4). All weights registerized
// f16x2 (grp0: 48 dw; grp1/2: 24+24 dw). 80KB LDS pad -> 1 WG/CU -> high
// VGPR budget (r20: VGPR=72, zero spill, zero conflicts). One TICK_BARRIER
// per tick. r22 edit: grp0 issues next-tick gi loads BEFORE the dot chain.
__global__ __launch_bounds__(640) void scan_kernel(
    const float* __restrict__ gi0,   // [B,Tc,N3]
    const float* __restrict__ w0hh, const float* __restrict__ w1ih,
    const float* __restrict__ w1hh, const float* __restrict__ w2ih,
    const float* __restrict__ w2hh,
    const float* __restrict__ b0hh, const float* __restrict__ b1ih,
    const float* __restrict__ b1hh, const float* __restrict__ b2ih,
    const float* __restrict__ b2hh,
    const int* __restrict__ act,     // [T]
    float* __restrict__ hstate,      // [3,B,H]
    float* __restrict__ out,         // [B,T,H]
    int t0, int Tc) {
  const int b   = blockIdx.x;
  const int tid = threadIdx.x;

  __shared__ __align__(16) char s_pad[81920];         // occupancy cap: 1 WG/CU
  __shared__ __align__(16) _Float16 s_h[3][2][H_];    // [layer][parity][unit]
  __shared__ int s_act[T_];

  if (tid == 0) { volatile char* vp = s_pad; vp[0] = 0; }  // keep pad alive

  for (int i = tid; i < Tc; i += 640) s_act[i] = act[t0 + i];

  const int grp = (tid < 128) ? 0 : (tid < 384) ? 1 : 2;
  const int lt  = tid - ((grp == 0) ? 0 : (grp == 1) ? 128 : 384);
  const int jj  = (grp == 0) ? (lt >> 1) : (lt >> 2);
  const int gg  = (grp == 0) ? (lt & 1) : (lt & 3);

  if (tid < H_) {
    float v0 = (t0 == 0) ? 0.f : hstate[0 * B_ * H_ + b * H_ + tid];
    float v1 = (t0 == 0) ? 0.f : hstate[1 * B_ * H_ + b * H_ + tid];
    float v2 = (t0 == 0) ? 0.f : hstate[2 * B_ * H_ + b * H_ + tid];
    s_h[0][0][tid] = (_Float16)v0; s_h[0][1][tid] = (_Float16)v0;
    s_h[1][0][tid] = (_Float16)v1; s_h[1][1][tid] = (_Float16)v1;
    s_h[2][0][tid] = (_Float16)v2; s_h[2][1][tid] = (_Float16)v2;
  }
  float hreg = (t0 == 0) ? 0.f : hstate[grp * B_ * H_ + b * H_ + jj];

  // ---- register weights ----
  int rw0[3][16];   // grp0: W0hh rows {jj,jj+64,jj+128}, cols [32gg,32gg+32)
  int rpk[3][8];    // grp1/2: Wih rows, cols [16gg,16gg+16)
  int rhh[3][8];    // grp1/2: Whh rows, cols [16gg,16gg+16)
  if (grp == 0) {
#pragma unroll
    for (int r = 0; r < 3; ++r) {
      const float* src = w0hh + (size_t)(jj + 64 * r) * H_ + 32 * gg;
#pragma unroll
      for (int q = 0; q < 16; ++q) {
        float2 fv = *(const float2*)(src + 2 * q);
        h2v pv = {(_Float16)fv.x, (_Float16)fv.y};
        rw0[r][q] = __builtin_bit_cast(int, pv);
      }
    }
#pragma unroll
    for (int r = 0; r < 3; ++r)
#pragma unroll
      for (int q = 0; q < 16; ++q) KEEP(rw0[r][q]);
  } else {
    const float* ihsrc = (grp == 2) ? w2ih : w1ih;
    const float* hhsrc = (grp == 2) ? w2hh : w1hh;
#pragma unroll
    for (int r = 0; r < 3; ++r) {
      const float* si = ihsrc + (size_t)(jj + 64 * r) * H_ + 16 * gg;
      const float* sh = hhsrc + (size_t)(jj + 64 * r) * H_ + 16 * gg;
#pragma unroll
      for (int q = 0; q < 8; ++q) {
        float2 fi = *(const float2*)(si + 2 * q);
        float2 fh = *(const float2*)(sh + 2 * q);
        h2v pi = {(_Float16)fi.x, (_Float16)fi.y};
        h2v ph = {(_Float16)fh.x, (_Float16)fh.y};
        rpk[r][q] = __builtin_bit_cast(int, pi);
        rhh[r][q] = __builtin_bit_cast(int, ph);
      }
    }
#pragma unroll
    for (int r = 0; r < 3; ++r)
#pragma unroll
      for (int q = 0; q < 8; ++q) { KEEP(rpk[r][q]); KEEP(rhh[r][q]); }
  }

  // biases: [0]=R combined, [1]=Z combined, [2]=ih_N, [3]=hh_N
  float bsv[4];
  if (grp == 0) {
    bsv[0] = 0.f; bsv[1] = 0.f; bsv[2] = 0.f;
    bsv[3] = b0hh[jj + 128];
  } else if (grp == 1) {
    bsv[0] = b1ih[jj] + b1hh[jj];
    bsv[1] = b1ih[jj + 64] + b1hh[jj + 64];
    bsv[2] = b1ih[jj + 128]; bsv[3] = b1hh[jj + 128];
  } else {
    bsv[0] = b2ih[jj] + b2hh[jj];
    bsv[1] = b2ih[jj + 64] + b2hh[jj + 64];
    bsv[2] = b2ih[jj + 128]; bsv[3] = b2hh[jj + 128];
  }

  const float* gib = gi0 + (size_t)b * Tc * N3;
  float giR = 0.f, giZ = 0.f, giN = 0.f;
  if (grp == 0) { giR = gib[jj]; giZ = gib[jj + 64]; giN = gib[jj + 128]; }

  __syncthreads();   // initial full barrier

  for (int i = 0; i < Tc + 2; ++i) {
    const int p = i & 1;
    if (grp == 0) {
      if (i < Tc) {
        // ---- prefetch next-tick gi FIRST (hoisted: max slack before use) ----
        int tn = (i + 1 < Tc) ? i + 1 : i;
        float nR = gib[(size_t)tn * N3 + jj];
        float nZ = gib[(size_t)tn * N3 + jj + 64];
        float nN = gib[(size_t)tn * N3 + jj + 128];

        const int4* hp = (const int4*)s_h[0][p ^ 1];
        int4 h0s = hp[4 * gg + 0], h1s = hp[4 * gg + 1];
        int4 h2s = hp[4 * gg + 2], h3s = hp[4 * gg + 3];
        float R0 = 0, R1 = 0, Z0 = 0, Z1 = 0, N0 = 0, N1 = 0;
        dot16reg(rw0[0], h0s, h1s, h2s, h3s, R0, R1);
        dot16reg(rw0[1], h0s, h1s, h2s, h3s, Z0, Z1);
        dot16reg(rw0[2], h0s, h1s, h2s, h3s, N0, N1);
        float dR = red2(R0 + R1);
        float dZ = red2(Z0 + Z1);
        float dN = red2(N0 + N1) + bsv[3];
        bool a = (s_act[i] != 0);
        float r = sigm_f(giR + dR);
        float z = sigm_f(giZ + dZ);
        float n = tanh_f(giN + r * dN);
        float hn = (1.0f - z) * n + z * hreg;
        hreg = a ? hn : hreg;
        if (gg == 0) s_h[0][p][jj] = (_Float16)hreg;
        giR = nR; giZ = nZ; giN = nN;
      }
    } else if (grp == 1) {
      if (i >= 1 && i <= Tc) {
        const int4* h0p = (const int4*)s_h[0][p ^ 1];
        const int4* h1p = (const int4*)s_h[1][p ^ 1];
        int4 x0 = h0p[2 * gg], x1 = h0p[2 * gg + 1];
        int4 y0 = h1p[2 * gg], y1 = h1p[2 * gg + 1];
        float vR0 = 0, vR1 = 0, vZ0 = 0, vZ1 = 0;
        float iN0 = 0, iN1 = 0, hN0 = 0, hN1 = 0;
        dot8reg(rpk[0], x0, x1, vR0, vR1);
        dot8reg(rhh[0], y0, y1, vR0, vR1);
        dot8reg(rpk[1], x0, x1, vZ0, vZ1);
        dot8reg(rhh[1], y0, y1, vZ0, vZ1);
        dot8reg(rpk[2], x0, x1, iN0, iN1);
        dot8reg(rhh[2], y0, y1, hN0, hN1);
        float sR = red4(vR0 + vR1) + bsv[0];
        float sZ = red4(vZ0 + vZ1) + bsv[1];
        float iN = red4(iN0 + iN1) + bsv[2];
        float hN = red4(hN0 + hN1) + bsv[3];
        bool a = (s_act[i - 1] != 0);
        float r = sigm_f(sR);
        float z = sigm_f(sZ);
        float n = tanh_f(iN + r * hN);
        float hn = (1.0f - z) * n + z * hreg;
        hreg = a ? hn : hreg;
        if (gg == 0) s_h[1][p][jj] = (_Float16)hreg;
      }
    } else {
      if (i >= 2) {
        const int4* h1p = (const int4*)s_h[1][p ^ 1];
        const int4* h2p = (const int4*)s_h[2][p ^ 1];
        int4 x0 = h1p[2 * gg], x1 = h1p[2 * gg + 1];
        int4 y0 = h2p[2 * gg], y1 = h2p[2 * gg + 1];
        float vR0 = 0, vR1 = 0, vZ0 = 0, vZ1 = 0;
        float iN0 = 0, iN1 = 0, hN0 = 0, hN1 = 0;
        dot8reg(rpk[0], x0, x1, vR0, vR1);
        dot8reg(rhh[0], y0, y1, vR0, vR1);
        dot8reg(rpk[1], x0, x1, vZ0, vZ1);
        dot8reg(rhh[1], y0, y1, vZ0, vZ1);
        dot8reg(rpk[2], x0, x1, iN0, iN1);
        dot8reg(rhh[2], y0, y1, hN0, hN1);
        float sR = red4(vR0 + vR1) + bsv[0];
        float sZ = red4(vZ0 + vZ1) + bsv[1];
        float iN = red4(iN0 + iN1) + bsv[2];
        float hN = red4(hN0 + hN1) + bsv[3];
        bool a = (s_act[i - 2] != 0);
        float r = sigm_f(sR);
        float z = sigm_f(sZ);
        float n = tanh_f(iN + r * hN);
        float hn = (1.0f - z) * n + z * hreg;
        hreg = a ? hn : hreg;
        if (gg == 0) {
          s_h[2][p][jj] = (_Float16)hreg;
          out[((size_t)b * T_ + t0 + (i - 2)) * H_ + jj] = a ? hreg : 0.0f;
        }
      }
    }
    TICK_BARRIER();   // lgkmcnt(0)+s_barrier only
  }

  if (gg == 0) hstate[grp * B_ * H_ + b * H_ + jj] = hreg;
}

extern "C" void kernel_launch(void* const* d_in, const int* in_sizes, int n_in,
                              void* d_out, int out_size, void* d_ws, size_t ws_size,
                              hipStream_t stream) {
  const float* x    = (const float*)d_in[0];
  const float* w0ih = (const float*)d_in[1];
  const float* w0hh = (const float*)d_in[2];
  const float* b0ih = (const float*)d_in[3];
  const float* b0hh = (const float*)d_in[4];
  const float* w1ih = (const float*)d_in[5];
  const float* w1hh = (const float*)d_in[6];
  const float* b1ih = (const float*)d_in[7];
  const float* b1hh = (const float*)d_in[8];
  const float* w2ih = (const float*)d_in[9];
  const float* w2hh = (const float*)d_in[10];
  const float* b2ih = (const float*)d_in[11];
  const float* b2hh = (const float*)d_in[12];
  float* out = (float*)d_out;

  char* p = (char*)d_ws;
  int* act      = (int*)p;    p += 4096;
  float* hstate = (float*)p;  p += (size_t)3 * B_ * H_ * 4;
  size_t fixed = (size_t)(p - (char*)d_ws);

  int Tc = T_;
  while (Tc > 64 && fixed + (size_t)B_ * Tc * N3 * 4 > ws_size) Tc >>= 1;
  float* gi0 = (float*)p;

  hipMemsetAsync(act, 0, T_ * sizeof(int), stream);
  for (int t0 = 0; t0 < T_; t0 += Tc) {
    gemm_kernel<<<dim3(B_ * (Tc / 64) * 3), 256, 0, stream>>>(
        x, w0ih, b0ih, b0hh, gi0, act, t0, Tc);
    scan_kernel<<<B_, 640, 0, stream>>>(
        gi0, w0hh, w1ih, w1hh, w2ih, w2hh,
        b0hh, b1ih, b1hh, b2ih, b2hh, act, hstate, out, t0, Tc);
  }
}